// Round 1
// baseline (1416.031 us; speedup 1.0000x reference)
//
#include <hip/hip_runtime.h>

#define G 64
#define M 128
#define D 256
#define S 129

#define BM 64
#define BN 64
#define BK 16
#define PAD 4  // LDS row stride 68 floats = 272 B -> keeps float4 LDS reads 16B-aligned

// ---------------------------------------------------------------------------
// Generic projection GEMM: dst[row][n] = sum_d src[srcrow(row)*D + d] * W[d][n] + bias[n]
// srcrow(row) = (row>>7)*outer + (row&127) + off   (row = a*M + i)
// ---------------------------------------------------------------------------
__global__ __launch_bounds__(256) void proj_kernel(const float* __restrict__ src,
                                                   const float* __restrict__ W,
                                                   const float* __restrict__ bias,
                                                   float* __restrict__ dst,
                                                   int outer, int off) {
    __shared__ float As[BK][BM + PAD];   // transposed: As[k][m]
    __shared__ float Bs[BK][BN + PAD];   // direct:     Bs[k][n]
    const int tid = threadIdx.x;
    const int tx = tid & 15, ty = tid >> 4;
    const int m0 = blockIdx.y * BM;
    const int n0 = blockIdx.x * BN;

    const int lr = tid >> 2;           // 0..63  (row within A tile)
    const int lc = (tid & 3) * 4;      // 0,4,8,12 (col within BK)
    const int arow = m0 + lr;
    const int asrc_row = (arow >> 7) * outer + (arow & 127) + off;
    const float* aptr = src + (size_t)asrc_row * D;

    const int br = tid >> 4;           // 0..15
    const int bc = (tid & 15) * 4;     // 0..60

    float acc[4][4] = {};
    for (int k0 = 0; k0 < D; k0 += BK) {
        float4 av = *(const float4*)(aptr + k0 + lc);
        As[lc + 0][lr] = av.x;
        As[lc + 1][lr] = av.y;
        As[lc + 2][lr] = av.z;
        As[lc + 3][lr] = av.w;
        float4 bv = *(const float4*)(W + (size_t)(k0 + br) * D + n0 + bc);
        *(float4*)&Bs[br][bc] = bv;
        __syncthreads();
#pragma unroll
        for (int kk = 0; kk < BK; ++kk) {
            float4 a4 = *(const float4*)&As[kk][ty * 4];
            float4 b4 = *(const float4*)&Bs[kk][tx * 4];
            float ar[4] = {a4.x, a4.y, a4.z, a4.w};
            float brr[4] = {b4.x, b4.y, b4.z, b4.w};
#pragma unroll
            for (int i = 0; i < 4; ++i)
#pragma unroll
                for (int j = 0; j < 4; ++j)
                    acc[i][j] = fmaf(ar[i], brr[j], acc[i][j]);
        }
        __syncthreads();
    }
    float4 bb = *(const float4*)(bias + n0 + tx * 4);
#pragma unroll
    for (int i = 0; i < 4; ++i) {
        int row = m0 + ty * 4 + i;
        float4 o;
        o.x = acc[i][0] + bb.x;
        o.y = acc[i][1] + bb.y;
        o.z = acc[i][2] + bb.z;
        o.w = acc[i][3] + bb.w;
        *(float4*)(dst + (size_t)row * D + n0 + tx * 4) = o;
    }
}

// ---------------------------------------------------------------------------
// Scores: e[a,b,i,j] = exp( (Q'[a,i]·K'[b,j]) / 16 - 1e9*mask[a,i,j] )
// write e (unnormalized) into att region; atomically accumulate row sums
// row = 2a + (b>>5)    (the reshape(M,-1) softmax grouping)
// ---------------------------------------------------------------------------
__global__ __launch_bounds__(256) void scores_kernel(const float* __restrict__ Qp,
                                                     const float* __restrict__ Kp,
                                                     const float* __restrict__ mask,
                                                     float* __restrict__ att,
                                                     float* __restrict__ row_sum) {
    __shared__ float As[BK][BM + PAD];
    __shared__ float Bs[BK][BN + PAD];
    __shared__ float red[256];
    const int tid = threadIdx.x;
    const int tx = tid & 15, ty = tid >> 4;
    const int ab = blockIdx.z;
    const int a = ab >> 6, b = ab & 63;
    const int i0 = blockIdx.y * BM;
    const int j0 = blockIdx.x * BN;

    const int lr = tid >> 2;
    const int lc = (tid & 3) * 4;
    const float* aptr = Qp + (size_t)(a * M + i0 + lr) * D;
    const float* bptr = Kp + (size_t)(b * M + j0 + lr) * D;

    float acc[4][4] = {};
    for (int k0 = 0; k0 < D; k0 += BK) {
        float4 av = *(const float4*)(aptr + k0 + lc);
        As[lc + 0][lr] = av.x;
        As[lc + 1][lr] = av.y;
        As[lc + 2][lr] = av.z;
        As[lc + 3][lr] = av.w;
        float4 bv = *(const float4*)(bptr + k0 + lc);
        Bs[lc + 0][lr] = bv.x;
        Bs[lc + 1][lr] = bv.y;
        Bs[lc + 2][lr] = bv.z;
        Bs[lc + 3][lr] = bv.w;
        __syncthreads();
#pragma unroll
        for (int kk = 0; kk < BK; ++kk) {
            float4 a4 = *(const float4*)&As[kk][ty * 4];
            float4 b4 = *(const float4*)&Bs[kk][tx * 4];
            float ar[4] = {a4.x, a4.y, a4.z, a4.w};
            float brr[4] = {b4.x, b4.y, b4.z, b4.w};
#pragma unroll
            for (int i = 0; i < 4; ++i)
#pragma unroll
                for (int j = 0; j < 4; ++j)
                    acc[i][j] = fmaf(ar[i], brr[j], acc[i][j]);
        }
        __syncthreads();
    }

    float tsum = 0.f;
#pragma unroll
    for (int i = 0; i < 4; ++i) {
        const int ig = i0 + ty * 4 + i;
        const float* mrow = mask + ((size_t)a * M + ig) * M + j0 + tx * 4;
        float e[4];
#pragma unroll
        for (int j = 0; j < 4; ++j) {
            float val = acc[i][j] * 0.0625f;           // 1/sqrt(256)
            float mv = mrow[j];
            e[j] = expf(fmaf(mv, -1e9f, val));         // masked -> exp(-1e9) == 0.0f
            tsum += e[j];
        }
        float4 e4 = {e[0], e[1], e[2], e[3]};
        *(float4*)(att + (((size_t)(a * G + b) * M + ig) * M + j0 + tx * 4)) = e4;
    }

    red[tid] = tsum;
    __syncthreads();
    for (int s = 128; s > 0; s >>= 1) {
        if (tid < s) red[tid] += red[tid + s];
        __syncthreads();
    }
    if (tid == 0) atomicAdd(&row_sum[2 * a + (b >> 5)], red[0]);
}

__global__ void inv_kernel(const float* __restrict__ rs, float* __restrict__ inv) {
    int t = threadIdx.x;
    if (t < 2 * G) inv[t] = 1.0f / rs[t];
}

// normalize att in place: att[idx] *= inv[idx>>19]
__global__ void norm_kernel(float* __restrict__ att, const float* __restrict__ inv) {
    size_t i = (size_t)blockIdx.x * blockDim.x + threadIdx.x;   // float4 index
    const size_t n4 = (size_t)G * G * M * M / 4;
    const size_t stride = (size_t)gridDim.x * blockDim.x;
    float4* p = (float4*)att;
    for (; i < n4; i += stride) {
        float iv = inv[i >> 17];   // (i*4)>>19
        float4 v = p[i];
        v.x *= iv; v.y *= iv; v.z *= iv; v.w *= iv;
        p[i] = v;
    }
}

// ---------------------------------------------------------------------------
// PV: out[a,i,d] = sum_{b,c} att_norm[a,b,i,c] * Vp[b*M + c][d]
// ---------------------------------------------------------------------------
__global__ __launch_bounds__(256) void pv_kernel(const float* __restrict__ attn,
                                                 const float* __restrict__ Vp,
                                                 float* __restrict__ outbuf) {
    __shared__ float As[BK][BM + PAD];   // As[c][i]
    __shared__ float Bs[BK][BN + PAD];   // Bs[c][d]
    const int tid = threadIdx.x;
    const int tx = tid & 15, ty = tid >> 4;
    const int a = blockIdx.z;
    const int i0 = blockIdx.y * BM;
    const int d0 = blockIdx.x * BN;

    const int lr = tid >> 2;
    const int lc = (tid & 3) * 4;
    const int br = tid >> 4;
    const int bc = (tid & 15) * 4;

    float acc[4][4] = {};
    for (int b = 0; b < G; ++b) {
        const float* abase = attn + ((size_t)(a * G + b) * M + i0 + lr) * M;
        const float* vbase = Vp + (size_t)b * M * D;
        for (int c0 = 0; c0 < M; c0 += BK) {
            float4 av = *(const float4*)(abase + c0 + lc);
            As[lc + 0][lr] = av.x;
            As[lc + 1][lr] = av.y;
            As[lc + 2][lr] = av.z;
            As[lc + 3][lr] = av.w;
            float4 bv = *(const float4*)(vbase + (size_t)(c0 + br) * D + d0 + bc);
            *(float4*)&Bs[br][bc] = bv;
            __syncthreads();
#pragma unroll
            for (int kk = 0; kk < BK; ++kk) {
                float4 a4 = *(const float4*)&As[kk][ty * 4];
                float4 b4 = *(const float4*)&Bs[kk][tx * 4];
                float ar[4] = {a4.x, a4.y, a4.z, a4.w};
                float brr[4] = {b4.x, b4.y, b4.z, b4.w};
#pragma unroll
                for (int i = 0; i < 4; ++i)
#pragma unroll
                    for (int j = 0; j < 4; ++j)
                        acc[i][j] = fmaf(ar[i], brr[j], acc[i][j]);
            }
            __syncthreads();
        }
    }
#pragma unroll
    for (int i = 0; i < 4; ++i) {
        int row = a * M + i0 + ty * 4 + i;
        float4 o = {acc[i][0], acc[i][1], acc[i][2], acc[i][3]};
        *(float4*)(outbuf + (size_t)row * D + d0 + tx * 4) = o;
    }
}

// ---------------------------------------------------------------------------
extern "C" void kernel_launch(void* const* d_in, const int* in_sizes, int n_in,
                              void* d_out, int out_size, void* d_ws, size_t ws_size,
                              hipStream_t stream) {
    const float* q    = (const float*)d_in[0];
    const float* k    = (const float*)d_in[1];
    const float* v    = (const float*)d_in[2];
    const float* mask = (const float*)d_in[3];
    const float* Wq   = (const float*)d_in[4];
    const float* bq   = (const float*)d_in[5];
    const float* Wk   = (const float*)d_in[6];
    const float* bk   = (const float*)d_in[7];
    const float* Wv   = (const float*)d_in[8];
    const float* bv   = (const float*)d_in[9];
    const float* Wo   = (const float*)d_in[10];
    const float* bo   = (const float*)d_in[11];

    float* out = (float*)d_out;                    // (G, M, D)
    float* att = out + (size_t)G * M * D;          // (G, G, M, M)

    float* ws      = (float*)d_ws;
    float* Qp      = ws;                           // 8 MB, dead after scores
    float* Kp      = Qp + (size_t)G * M * D;       // 8 MB
    float* Vp      = Kp + (size_t)G * M * D;       // 8 MB
    float* row_sum = Vp + (size_t)G * M * D;       // 128 floats
    float* invb    = row_sum + 2 * G;              // 128 floats
    float* outbuf  = Qp;                           // reuse Qp region for PV output

    hipMemsetAsync(row_sum, 0, 2 * G * sizeof(float), stream);

    dim3 blk(256);
    dim3 gproj(D / BN, (G * M) / BM);              // (4, 128)
    proj_kernel<<<gproj, blk, 0, stream>>>(q, Wq, bq, Qp, S, 1);  // Q' = qs[:,1:,:]
    proj_kernel<<<gproj, blk, 0, stream>>>(k, Wk, bk, Kp, S, 0);  // K' = ks[:,:M,:]
    proj_kernel<<<gproj, blk, 0, stream>>>(v, Wv, bv, Vp, M, 0);  // V'

    dim3 gsc(M / BN, M / BM, G * G);               // (2, 2, 4096)
    scores_kernel<<<gsc, blk, 0, stream>>>(Qp, Kp, mask, att, row_sum);

    inv_kernel<<<1, 128, 0, stream>>>(row_sum, invb);
    norm_kernel<<<2048, 256, 0, stream>>>(att, invb);

    dim3 gpv(D / BN, M / BM, G);                   // (4, 2, 64)
    pv_kernel<<<gpv, blk, 0, stream>>>(att, Vp, outbuf);

    proj_kernel<<<gproj, blk, 0, stream>>>(outbuf, Wo, bo, out, M, 0);
}

// Round 2
// 749.021 us; speedup vs baseline: 1.8905x; 1.8905x over previous
//
#include <hip/hip_runtime.h>
#include <hip/hip_bf16.h>

#define G 64
#define M 128
#define D 256
#define S 129

typedef short s16x8 __attribute__((ext_vector_type(8)));
typedef float f32x4 __attribute__((ext_vector_type(4)));

__device__ inline void gld16(const void* g, void* l) {
    __builtin_amdgcn_global_load_lds(
        (const __attribute__((address_space(1))) unsigned int*)g,
        (__attribute__((address_space(3))) unsigned int*)l, 16, 0, 0);
}

__device__ inline unsigned short f2bf(float f) {
    __hip_bfloat16 h = __float2bfloat16(f);
    return *reinterpret_cast<unsigned short*>(&h);
}

// ---------------------------------------------------------------------------
// fp32 projection, bf16 output. srcrow(row) = (row>>7)*outer + (row&127) + off
// ---------------------------------------------------------------------------
#define BM 64
#define BN 64
#define BK 16
#define PAD 4
__global__ __launch_bounds__(256) void proj_bf16(const float* __restrict__ src,
                                                 const float* __restrict__ W,
                                                 const float* __restrict__ bias,
                                                 unsigned short* __restrict__ dstb,
                                                 int outer, int off) {
    __shared__ float As[BK][BM + PAD];
    __shared__ float Bs[BK][BN + PAD];
    const int tid = threadIdx.x;
    const int tx = tid & 15, ty = tid >> 4;
    const int m0 = blockIdx.y * BM;
    const int n0 = blockIdx.x * BN;
    const int lr = tid >> 2;
    const int lc = (tid & 3) * 4;
    const int arow = m0 + lr;
    const int asrc_row = (arow >> 7) * outer + (arow & 127) + off;
    const float* aptr = src + (size_t)asrc_row * D;
    const int br = tid >> 4;
    const int bc = (tid & 15) * 4;

    float acc[4][4] = {};
    for (int k0 = 0; k0 < D; k0 += BK) {
        float4 av = *(const float4*)(aptr + k0 + lc);
        As[lc + 0][lr] = av.x; As[lc + 1][lr] = av.y;
        As[lc + 2][lr] = av.z; As[lc + 3][lr] = av.w;
        float4 bv = *(const float4*)(W + (size_t)(k0 + br) * D + n0 + bc);
        *(float4*)&Bs[br][bc] = bv;
        __syncthreads();
#pragma unroll
        for (int kk = 0; kk < BK; ++kk) {
            float4 a4 = *(const float4*)&As[kk][ty * 4];
            float4 b4 = *(const float4*)&Bs[kk][tx * 4];
            float ar[4] = {a4.x, a4.y, a4.z, a4.w};
            float brr[4] = {b4.x, b4.y, b4.z, b4.w};
#pragma unroll
            for (int i = 0; i < 4; ++i)
#pragma unroll
                for (int j = 0; j < 4; ++j)
                    acc[i][j] = fmaf(ar[i], brr[j], acc[i][j]);
        }
        __syncthreads();
    }
    float4 bb = *(const float4*)(bias + n0 + tx * 4);
#pragma unroll
    for (int i = 0; i < 4; ++i) {
        int row = m0 + ty * 4 + i;
        ushort4 o;
        o.x = f2bf(acc[i][0] + bb.x);
        o.y = f2bf(acc[i][1] + bb.y);
        o.z = f2bf(acc[i][2] + bb.z);
        o.w = f2bf(acc[i][3] + bb.w);
        *(ushort4*)(dstb + (size_t)row * D + n0 + tx * 4) = o;
    }
}

// fp32 projection of (s0+s1), fp32 output, identity row map (final O-proj)
__global__ __launch_bounds__(256) void projo_kernel(const float* __restrict__ s0,
                                                    const float* __restrict__ s1,
                                                    const float* __restrict__ W,
                                                    const float* __restrict__ bias,
                                                    float* __restrict__ dst) {
    __shared__ float As[BK][BM + PAD];
    __shared__ float Bs[BK][BN + PAD];
    const int tid = threadIdx.x;
    const int tx = tid & 15, ty = tid >> 4;
    const int m0 = blockIdx.y * BM;
    const int n0 = blockIdx.x * BN;
    const int lr = tid >> 2;
    const int lc = (tid & 3) * 4;
    const int br = tid >> 4;
    const int bc = (tid & 15) * 4;

    float acc[4][4] = {};
    for (int k0 = 0; k0 < D; k0 += BK) {
        float4 a0 = *(const float4*)(s0 + (size_t)(m0 + lr) * D + k0 + lc);
        float4 a1 = *(const float4*)(s1 + (size_t)(m0 + lr) * D + k0 + lc);
        As[lc + 0][lr] = a0.x + a1.x; As[lc + 1][lr] = a0.y + a1.y;
        As[lc + 2][lr] = a0.z + a1.z; As[lc + 3][lr] = a0.w + a1.w;
        float4 bv = *(const float4*)(W + (size_t)(k0 + br) * D + n0 + bc);
        *(float4*)&Bs[br][bc] = bv;
        __syncthreads();
#pragma unroll
        for (int kk = 0; kk < BK; ++kk) {
            float4 a4 = *(const float4*)&As[kk][ty * 4];
            float4 b4 = *(const float4*)&Bs[kk][tx * 4];
            float ar[4] = {a4.x, a4.y, a4.z, a4.w};
            float brr[4] = {b4.x, b4.y, b4.z, b4.w};
#pragma unroll
            for (int i = 0; i < 4; ++i)
#pragma unroll
                for (int j = 0; j < 4; ++j)
                    acc[i][j] = fmaf(ar[i], brr[j], acc[i][j]);
        }
        __syncthreads();
    }
    float4 bb = *(const float4*)(bias + n0 + tx * 4);
#pragma unroll
    for (int i = 0; i < 4; ++i) {
        int row = m0 + ty * 4 + i;
        float4 o;
        o.x = acc[i][0] + bb.x; o.y = acc[i][1] + bb.y;
        o.z = acc[i][2] + bb.z; o.w = acc[i][3] + bb.w;
        *(float4*)(dst + (size_t)row * D + n0 + tx * 4) = o;
    }
}

// ---------------------------------------------------------------------------
// transpose Vb [8192][256] bf16 -> Vt [256][8192] bf16
// ---------------------------------------------------------------------------
__global__ __launch_bounds__(256) void transpose_kernel(const unsigned short* __restrict__ in,
                                                        unsigned short* __restrict__ out) {
    __shared__ unsigned short t[64][68];
    const int c0 = blockIdx.x * 64;
    const int r0 = blockIdx.y * 64;
    const int lr = threadIdx.x >> 4;
    const int lc = (threadIdx.x & 15) * 4;
#pragma unroll
    for (int p = 0; p < 4; ++p) {
        int row = p * 16 + lr;
        ushort4 v = *(const ushort4*)(in + (size_t)(r0 + row) * D + c0 + lc);
        t[lc + 0][row] = v.x; t[lc + 1][row] = v.y;
        t[lc + 2][row] = v.z; t[lc + 3][row] = v.w;
    }
    __syncthreads();
#pragma unroll
    for (int p = 0; p < 4; ++p) {
        int dr = p * 16 + lr;
        ushort4 v = *(const ushort4*)(&t[dr][lc]);
        *(ushort4*)(out + (size_t)(c0 + dr) * (G * M) + r0 + lc) = v;
    }
}

// ---------------------------------------------------------------------------
// scores: block = one (a,b), 128x128 out, K=256. 4 waves (2x2), MFMA 16x16x32.
// LDS tiles [128][32] bf16, XOR-swizzled 16B slots, global_load_lds staging.
// ---------------------------------------------------------------------------
__global__ __launch_bounds__(256) void scores_mfma(const unsigned short* __restrict__ Qb,
                                                   const unsigned short* __restrict__ Kb,
                                                   const float* __restrict__ mask,
                                                   float* __restrict__ att,
                                                   float* __restrict__ row_sum) {
    __shared__ __align__(16) char sm[32768];  // A:[0,16K) x2, B:[16K,32K) x2
    const int tid = threadIdx.x;
    const int ab = blockIdx.x;
    const int a = ab >> 6, b = ab & 63;
    const int w = tid >> 6, l = tid & 63;
    const int wi = w >> 1, wj = w & 1;

    const unsigned short* qbase = Qb + (size_t)a * M * D;
    const unsigned short* kbase = Kb + (size_t)b * M * D;

    const int s0 = tid, s1 = tid + 256;
    const int r0s = s0 >> 2, r1s = s1 >> 2;
    const int g0 = (((s0 & 3) ^ ((r0s >> 1) & 3)) * 8);
    const int g1 = (((s1 & 3) ^ ((r1s >> 1) & 3)) * 8);
    const int slotp = (((l >> 4) ^ (((l & 15) >> 1) & 3)) << 4);  // read-side swizzled 16B slot

    f32x4 acc[4][4] = {};

#define SC_STAGE(buf, t)                                                        \
    do {                                                                        \
        int k0 = (t) * 32;                                                      \
        gld16(qbase + (size_t)r0s * D + k0 + g0, sm + (buf)*8192 + s0 * 16);    \
        gld16(qbase + (size_t)r1s * D + k0 + g1, sm + (buf)*8192 + s1 * 16);    \
        gld16(kbase + (size_t)r0s * D + k0 + g0, sm + 16384 + (buf)*8192 + s0 * 16); \
        gld16(kbase + (size_t)r1s * D + k0 + g1, sm + 16384 + (buf)*8192 + s1 * 16); \
    } while (0)

    SC_STAGE(0, 0);
    __syncthreads();
    for (int t = 0; t < 8; ++t) {
        const int buf = t & 1;
        if (t < 7) SC_STAGE(buf ^ 1, t + 1);
        s16x8 af[4], bf[4];
#pragma unroll
        for (int f = 0; f < 4; ++f) {
            af[f] = *(const s16x8*)(sm + buf * 8192 + (wi * 64 + f * 16 + (l & 15)) * 64 + slotp);
            bf[f] = *(const s16x8*)(sm + 16384 + buf * 8192 + (wj * 64 + f * 16 + (l & 15)) * 64 + slotp);
        }
#pragma unroll
        for (int i = 0; i < 4; ++i)
#pragma unroll
            for (int j = 0; j < 4; ++j)
                acc[i][j] = __builtin_amdgcn_mfma_f32_16x16x32_bf16(af[i], bf[j], acc[i][j], 0, 0, 0);
        __syncthreads();
    }

    // epilogue: scale, mask, exp, write, block-sum
    float tsum = 0.f;
    const int ro = (l >> 4) * 4;
    const int co = l & 15;
#pragma unroll
    for (int i = 0; i < 4; ++i)
#pragma unroll
        for (int j = 0; j < 4; ++j) {
            const int jj = wj * 64 + j * 16 + co;
#pragma unroll
            for (int r = 0; r < 4; ++r) {
                const int ii = wi * 64 + i * 16 + ro + r;
                float val = acc[i][j][r] * 0.0625f;
                float mv = mask[((size_t)a * M + ii) * M + jj];
                float e = __expf(fmaf(mv, -1e9f, val));
                tsum += e;
                att[(((size_t)(a * G + b)) * M + ii) * M + jj] = e;
            }
        }
    __syncthreads();
    float* red = (float*)sm;
    red[tid] = tsum;
    __syncthreads();
    for (int st = 128; st > 0; st >>= 1) {
        if (tid < st) red[tid] += red[tid + st];
        __syncthreads();
    }
    if (tid == 0) atomicAdd(&row_sum[2 * a + (b >> 5)], red[0]);
}

__global__ void inv_kernel(const float* __restrict__ rs, float* __restrict__ inv) {
    int t = threadIdx.x;
    if (t < 2 * G) inv[t] = 1.0f / rs[t];
}

// ---------------------------------------------------------------------------
// PV: block = (bhalf, i-quarter, a). Tile 32(i) x 256(d), K = 4096 (32 b x 128 c).
// Reads unnormalized e fp32 once, writes normalized att back, bf16 -> LDS, MFMA vs V^T.
// Partial outputs (per b-half) to P0/P1, summed in projo.
// ---------------------------------------------------------------------------
__global__ __launch_bounds__(256) void pv_mfma(float* __restrict__ att,
                                               const unsigned short* __restrict__ Vt,
                                               const float* __restrict__ invb,
                                               float* __restrict__ P0,
                                               float* __restrict__ P1) {
    __shared__ __align__(16) char sm[36864];  // A:[0,4K) x2(2K), B:[4K,36K) x2(16K)
    const int tid = threadIdx.x;
    const int bh = blockIdx.x;
    const int i0 = blockIdx.y * 32;
    const int a = blockIdx.z;
    const int w = tid >> 6, l = tid & 63;
    const float iv = invb[2 * a + bh];
    float* __restrict__ Pb = bh ? P1 : P0;

    // A staging: 32 rows x 32 c fp32; thread -> (row = tid>>3, quad aq = tid&7)
    const int ar = tid >> 3, aq = tid & 7;
    const int awbyte = ar * 64 + (((aq >> 1) ^ ((ar >> 1) & 3)) << 4) + (aq & 1) * 8;
    const int slotp = (((l >> 4) ^ (((l & 15) >> 1) & 3)) << 4);

    f32x4 acc[2][4] = {};

    size_t aoff_t = 0;  // recomputed per use
#define PV_AADDR(t) (att + ((size_t)(a * G + bh * 32 + ((t) >> 2)) * M + i0 + ar) * M + ((t) & 3) * 32 + aq * 4)

    auto BSTAGE = [&](int t) {
        const int buf = t & 1;
        const int kbase = bh * 4096 + t * 32;
#pragma unroll
        for (int k2 = 0; k2 < 4; ++k2) {
            int s = tid + 256 * k2;
            int d = s >> 2;
            int gsl = (((s & 3) ^ ((d >> 1) & 3)) * 8);
            gld16(Vt + (size_t)d * (G * M) + kbase + gsl, sm + 4096 + buf * 16384 + s * 16);
        }
    };
    auto AFIN = [&](int t, f32x4 v) {
        f32x4 wv = v * iv;
        *(f32x4*)PV_AADDR(t) = wv;  // normalized att writeback
        unsigned long long pk = (unsigned long long)f2bf(wv[0]) |
                                ((unsigned long long)f2bf(wv[1]) << 16) |
                                ((unsigned long long)f2bf(wv[2]) << 32) |
                                ((unsigned long long)f2bf(wv[3]) << 48);
        *(unsigned long long*)(sm + (t & 1) * 2048 + awbyte) = pk;
    };

    {
        f32x4 av = *(const f32x4*)PV_AADDR(0);
        BSTAGE(0);
        AFIN(0, av);
    }
    __syncthreads();

    for (int t = 0; t < 128; ++t) {
        const int buf = t & 1;
        f32x4 nv;
        if (t < 127) {
            nv = *(const f32x4*)PV_AADDR(t + 1);  // issue early, consume after MFMA
            BSTAGE(t + 1);
        }
        s16x8 af[2], bf[4];
#pragma unroll
        for (int f = 0; f < 2; ++f)
            af[f] = *(const s16x8*)(sm + buf * 2048 + (f * 16 + (l & 15)) * 64 + slotp);
#pragma unroll
        for (int f = 0; f < 4; ++f)
            bf[f] = *(const s16x8*)(sm + 4096 + buf * 16384 + (w * 64 + f * 16 + (l & 15)) * 64 + slotp);
#pragma unroll
        for (int i = 0; i < 2; ++i)
#pragma unroll
            for (int j = 0; j < 4; ++j)
                acc[i][j] = __builtin_amdgcn_mfma_f32_16x16x32_bf16(af[i], bf[j], acc[i][j], 0, 0, 0);
        if (t < 127) AFIN(t + 1, nv);
        __syncthreads();
    }

#pragma unroll
    for (int i = 0; i < 2; ++i)
#pragma unroll
        for (int j = 0; j < 4; ++j)
#pragma unroll
            for (int r = 0; r < 4; ++r) {
                const int ii = i0 + i * 16 + (l >> 4) * 4 + r;
                const int dd = w * 64 + j * 16 + (l & 15);
                Pb[((size_t)a * M + ii) * D + dd] = acc[i][j][r];
            }
}

// ---------------------------------------------------------------------------
extern "C" void kernel_launch(void* const* d_in, const int* in_sizes, int n_in,
                              void* d_out, int out_size, void* d_ws, size_t ws_size,
                              hipStream_t stream) {
    const float* q    = (const float*)d_in[0];
    const float* k    = (const float*)d_in[1];
    const float* v    = (const float*)d_in[2];
    const float* mask = (const float*)d_in[3];
    const float* Wq   = (const float*)d_in[4];
    const float* bq   = (const float*)d_in[5];
    const float* Wk   = (const float*)d_in[6];
    const float* bk   = (const float*)d_in[7];
    const float* Wv   = (const float*)d_in[8];
    const float* bv   = (const float*)d_in[9];
    const float* Wo   = (const float*)d_in[10];
    const float* bo   = (const float*)d_in[11];

    float* out = (float*)d_out;                    // (G, M, D)
    float* att = out + (size_t)G * M * D;          // (G, G, M, M)

    const size_t NE = (size_t)G * M * D;           // 2,097,152
    unsigned short* Qbf = (unsigned short*)d_ws;   // [0, 4MB)
    unsigned short* Kbf = Qbf + NE;                // [4, 8MB)
    unsigned short* Vbf = Kbf + NE;                // [8, 12MB)  dead after transpose
    unsigned short* Vt  = Vbf + NE;                // [12, 16MB) live through PV
    float* row_sum = (float*)Vbf;                  // reuse Vbf region after transpose
    float* invb    = row_sum + 128;
    float* P0 = (float*)d_ws;                      // [0, 8MB)  overlays Qbf/Kbf (dead)
    float* P1 = (float*)((char*)d_ws + (size_t)16 * 1024 * 1024);  // [16, 24MB)

    dim3 blk(256);
    dim3 gproj(D / BN, (G * M) / BM);              // (4, 128)
    proj_bf16<<<gproj, blk, 0, stream>>>(q, Wq, bq, Qbf, S, 1);
    proj_bf16<<<gproj, blk, 0, stream>>>(k, Wk, bk, Kbf, S, 0);
    proj_bf16<<<gproj, blk, 0, stream>>>(v, Wv, bv, Vbf, M, 0);

    transpose_kernel<<<dim3(D / 64, (G * M) / 64), blk, 0, stream>>>(Vbf, Vt);

    hipMemsetAsync(row_sum, 0, 2 * G * sizeof(float), stream);

    scores_mfma<<<dim3(G * G), blk, 0, stream>>>(Qbf, Kbf, mask, att, row_sum);

    inv_kernel<<<1, 128, 0, stream>>>(row_sum, invb);

    pv_mfma<<<dim3(2, 4, G), blk, 0, stream>>>(att, Vt, invb, P0, P1);

    projo_kernel<<<gproj, blk, 0, stream>>>(P0, P1, Wo, bo, out);
}

// Round 5
// 667.667 us; speedup vs baseline: 2.1209x; 1.1218x over previous
//
#include <hip/hip_runtime.h>
#include <hip/hip_bf16.h>

#define G 64
#define M 128
#define D 256
#define S 129

typedef short s16x8 __attribute__((ext_vector_type(8)));
typedef float f32x4 __attribute__((ext_vector_type(4)));

__device__ inline void gld16(const void* g, void* l) {
    __builtin_amdgcn_global_load_lds(
        (const __attribute__((address_space(1))) unsigned int*)g,
        (__attribute__((address_space(3))) unsigned int*)l, 16, 0, 0);
}

__device__ inline unsigned short f2bf(float f) {
    __hip_bfloat16 h = __float2bfloat16(f);
    return *reinterpret_cast<unsigned short*>(&h);
}

// ---------------------------------------------------------------------------
// fp32 -> bf16 vectorized convert
// ---------------------------------------------------------------------------
__global__ __launch_bounds__(256) void cvt_kernel(const float* __restrict__ src,
                                                  unsigned short* __restrict__ dst, int n4) {
    int i = blockIdx.x * 256 + threadIdx.x;
    if (i >= n4) return;
    float4 v = ((const float4*)src)[i];
    ushort4 o = {f2bf(v.x), f2bf(v.y), f2bf(v.z), f2bf(v.w)};
    ((ushort4*)dst)[i] = o;
}

// transpose+convert W [256 k][256 n] f32 -> WT [256 n][256 k] bf16
__global__ __launch_bounds__(256) void wt_kernel(const float* __restrict__ in,
                                                 unsigned short* __restrict__ out) {
    __shared__ float t[64][68];
    const int c0 = blockIdx.x * 64;   // n
    const int r0 = blockIdx.y * 64;   // k
    const int lr = threadIdx.x >> 4;
    const int lc = (threadIdx.x & 15) * 4;
#pragma unroll
    for (int p = 0; p < 4; ++p) {
        int row = p * 16 + lr;
        float4 v = *(const float4*)(in + (size_t)(r0 + row) * D + c0 + lc);
        t[lc + 0][row] = v.x; t[lc + 1][row] = v.y;
        t[lc + 2][row] = v.z; t[lc + 3][row] = v.w;
    }
    __syncthreads();
#pragma unroll
    for (int p = 0; p < 4; ++p) {
        int dr = p * 16 + lr;
        ushort4 o = {f2bf(t[dr][lc]), f2bf(t[dr][lc + 1]), f2bf(t[dr][lc + 2]), f2bf(t[dr][lc + 3])};
        *(ushort4*)(out + (size_t)(c0 + dr) * D + r0 + lc) = o;
    }
}

// ---------------------------------------------------------------------------
// bf16 MFMA projection: dst = rowmap(src) @ WT^T + bias
// out tile 128m x 64n, 4 waves (2x2), K=256 in 8 steps, gld16 dbuf staging.
// A dbuf: 2 x 8192 B @0.  B tile = 64 rows x 32 k x 2B = 4096 B -> dbuf 2 x 4096 @16384.
// transposed=0: dst[m][n] bf16 ; transposed=1: dst[n][8192 + m] bf16 (V^T)
// ---------------------------------------------------------------------------
__global__ __launch_bounds__(256) void proj_mfma(const unsigned short* __restrict__ src,
                                                 const unsigned short* __restrict__ WT,
                                                 const float* __restrict__ bias,
                                                 unsigned short* __restrict__ dst,
                                                 int outer, int off, int transposed) {
    __shared__ __align__(16) char sm[24576];
    const int tid = threadIdx.x;
    const int w = tid >> 6, l = tid & 63;
    const int wi = w >> 1, wj = w & 1;
    const int m0 = blockIdx.y * 128;
    const int n0 = blockIdx.x * 64;

    const int s0 = tid, s1 = tid + 256;
    const int ar0 = s0 >> 2, ar1 = s1 >> 2;
    const int g0 = (((s0 & 3) ^ ((ar0 >> 1) & 3)) * 8);
    const int g1 = (((s1 & 3) ^ ((ar1 >> 1) & 3)) * 8);
    const int am0 = m0 + ar0, am1 = m0 + ar1;
    const size_t asrc0 = (size_t)((am0 >> 7) * outer + (am0 & 127) + off) * D;
    const size_t asrc1 = (size_t)((am1 >> 7) * outer + (am1 & 127) + off) * D;
    const int brw = tid >> 2;
    const int gb = (((tid & 3) ^ ((brw >> 1) & 3)) * 8);
    const size_t bsrc = (size_t)(n0 + brw) * D;
    const int slotp = (((l >> 4) ^ (((l & 15) >> 1) & 3)) << 4);

    f32x4 acc[4][2] = {};

#define PJ_STAGE(buf, t)                                                  \
    do {                                                                  \
        int k0 = (t) * 32;                                                \
        gld16(src + asrc0 + k0 + g0, sm + (buf)*8192 + s0 * 16);          \
        gld16(src + asrc1 + k0 + g1, sm + (buf)*8192 + s1 * 16);          \
        gld16(WT + bsrc + k0 + gb, sm + 16384 + (buf)*4096 + tid * 16);   \
    } while (0)

    PJ_STAGE(0, 0);
    __syncthreads();
    for (int t = 0; t < 8; ++t) {
        const int buf = t & 1;
        if (t < 7) PJ_STAGE(buf ^ 1, t + 1);
        s16x8 af[4], bfr[2];
#pragma unroll
        for (int f = 0; f < 4; ++f)
            af[f] = *(const s16x8*)(sm + buf * 8192 + (wi * 64 + f * 16 + (l & 15)) * 64 + slotp);
#pragma unroll
        for (int f = 0; f < 2; ++f)
            bfr[f] = *(const s16x8*)(sm + 16384 + buf * 4096 + (wj * 32 + f * 16 + (l & 15)) * 64 + slotp);
#pragma unroll
        for (int i = 0; i < 4; ++i)
#pragma unroll
            for (int j = 0; j < 2; ++j)
                acc[i][j] = __builtin_amdgcn_mfma_f32_16x16x32_bf16(af[i], bfr[j], acc[i][j], 0, 0, 0);
        __syncthreads();
    }

#pragma unroll
    for (int i = 0; i < 4; ++i)
#pragma unroll
        for (int j = 0; j < 2; ++j) {
            const int col = n0 + wj * 32 + j * 16 + (l & 15);
            const int row0 = m0 + wi * 64 + i * 16 + (l >> 4) * 4;
            const float bb = bias[col];
            if (transposed) {
                ushort4 o = {f2bf(acc[i][j][0] + bb), f2bf(acc[i][j][1] + bb),
                             f2bf(acc[i][j][2] + bb), f2bf(acc[i][j][3] + bb)};
                *(ushort4*)(dst + (size_t)col * (G * M) + row0) = o;
            } else {
#pragma unroll
                for (int r = 0; r < 4; ++r)
                    dst[(size_t)(row0 + r) * D + col] = f2bf(acc[i][j][r] + bb);
            }
        }
}

// ---------------------------------------------------------------------------
// scores: block = one (a,b), 128x128 out, K=256 (verified round 2)
// ---------------------------------------------------------------------------
__global__ __launch_bounds__(256) void scores_mfma(const unsigned short* __restrict__ Qb,
                                                   const unsigned short* __restrict__ Kb,
                                                   const float* __restrict__ mask,
                                                   float* __restrict__ att,
                                                   float* __restrict__ row_sum) {
    __shared__ __align__(16) char sm[32768];
    const int tid = threadIdx.x;
    const int ab = blockIdx.x;
    const int a = ab >> 6, b = ab & 63;
    const int w = tid >> 6, l = tid & 63;
    const int wi = w >> 1, wj = w & 1;

    const unsigned short* qbase = Qb + (size_t)a * M * D;
    const unsigned short* kbase = Kb + (size_t)b * M * D;

    const int s0 = tid, s1 = tid + 256;
    const int r0s = s0 >> 2, r1s = s1 >> 2;
    const int g0 = (((s0 & 3) ^ ((r0s >> 1) & 3)) * 8);
    const int g1 = (((s1 & 3) ^ ((r1s >> 1) & 3)) * 8);
    const int slotp = (((l >> 4) ^ (((l & 15) >> 1) & 3)) << 4);

    f32x4 acc[4][4] = {};

#define SC_STAGE(buf, t)                                                        \
    do {                                                                        \
        int k0 = (t) * 32;                                                      \
        gld16(qbase + (size_t)r0s * D + k0 + g0, sm + (buf)*8192 + s0 * 16);    \
        gld16(qbase + (size_t)r1s * D + k0 + g1, sm + (buf)*8192 + s1 * 16);    \
        gld16(kbase + (size_t)r0s * D + k0 + g0, sm + 16384 + (buf)*8192 + s0 * 16); \
        gld16(kbase + (size_t)r1s * D + k0 + g1, sm + 16384 + (buf)*8192 + s1 * 16); \
    } while (0)

    SC_STAGE(0, 0);
    __syncthreads();
    for (int t = 0; t < 8; ++t) {
        const int buf = t & 1;
        if (t < 7) SC_STAGE(buf ^ 1, t + 1);
        s16x8 af[4], bfr[4];
#pragma unroll
        for (int f = 0; f < 4; ++f) {
            af[f] = *(const s16x8*)(sm + buf * 8192 + (wi * 64 + f * 16 + (l & 15)) * 64 + slotp);
            bfr[f] = *(const s16x8*)(sm + 16384 + buf * 8192 + (wj * 64 + f * 16 + (l & 15)) * 64 + slotp);
        }
#pragma unroll
        for (int i = 0; i < 4; ++i)
#pragma unroll
            for (int j = 0; j < 4; ++j)
                acc[i][j] = __builtin_amdgcn_mfma_f32_16x16x32_bf16(af[i], bfr[j], acc[i][j], 0, 0, 0);
        __syncthreads();
    }

    float tsum = 0.f;
    const int ro = (l >> 4) * 4;
    const int co = l & 15;
#pragma unroll
    for (int i = 0; i < 4; ++i)
#pragma unroll
        for (int j = 0; j < 4; ++j) {
            const int jj = wj * 64 + j * 16 + co;
#pragma unroll
            for (int r = 0; r < 4; ++r) {
                const int ii = wi * 64 + i * 16 + ro + r;
                float val = acc[i][j][r] * 0.0625f;
                float mv = mask[((size_t)a * M + ii) * M + jj];
                float e = __expf(fmaf(mv, -1e9f, val));
                tsum += e;
                att[(((size_t)(a * G + b)) * M + ii) * M + jj] = e;
            }
        }
    __syncthreads();
    float* red = (float*)sm;
    red[tid] = tsum;
    __syncthreads();
    for (int st = 128; st > 0; st >>= 1) {
        if (tid < st) red[tid] += red[tid + st];
        __syncthreads();
    }
    if (tid == 0) atomicAdd(&row_sum[2 * a + (b >> 5)], red[0]);
}

__global__ void inv_kernel(const float* __restrict__ rs, float* __restrict__ inv) {
    int t = threadIdx.x;
    if (t < 2 * G) inv[t] = 1.0f / rs[t];
}

// ---------------------------------------------------------------------------
// pv2: block = (kh, ih, a). out tile 64i x 256d, K=4096 (32 b-planes).
// Per half-plane: A = att fp32 -> normalize -> writeback -> bf16 LDS;
//                 B = V^T via gld16. XOR slot swizzle (^row&7). 8 waves.
// ---------------------------------------------------------------------------
__global__ __launch_bounds__(512) void pv2(float* __restrict__ att,
                                           const unsigned short* __restrict__ Vt,
                                           const float* __restrict__ invb,
                                           float* __restrict__ P0,
                                           float* __restrict__ P1) {
    __shared__ __align__(16) char sm[81920];  // A dbuf 2x8K @0, B dbuf 2x32K @16384
    const int tid = threadIdx.x;
    const int kh = blockIdx.x, ih = blockIdx.y, a = blockIdx.z;
    const int w = tid >> 6, l = tid & 63;
    const int wr = w >> 2, wc = w & 3;
    const float iv = invb[2 * a + kh];
    float* __restrict__ Pb = kh ? P1 : P0;

    const int arow = tid >> 3, aslot = tid & 7;
    const int ajsw = ((aslot ^ (arow & 7)) * 8);
    f32x4 acc[2][4] = {};

#define PV_STAGE(buf, hp)                                                           \
    do {                                                                            \
        const int p_ = (hp) >> 1, kb_ = ((hp) & 1) * 64;                            \
        _Pragma("unroll")                                                           \
        for (int u = 0; u < 4; ++u) {                                               \
            int cb = u * 512 + tid;                                                 \
            int brow = cb >> 3, bslot = cb & 7;                                     \
            gld16(Vt + (size_t)brow * (G * M) + kh * 4096 + p_ * 128 + kb_ +        \
                      ((bslot ^ (brow & 7)) * 8),                                   \
                  sm + 16384 + (buf)*32768 + cb * 16);                              \
        }                                                                           \
        float* ap = att + (((size_t)(a * G + kh * 32 + p_) * M) + ih * 64 + arow) * M + kb_ + ajsw; \
        float4 v0 = *(float4*)ap;                                                   \
        float4 v1 = *(float4*)(ap + 4);                                             \
        float4 w0 = {v0.x * iv, v0.y * iv, v0.z * iv, v0.w * iv};                   \
        float4 w1 = {v1.x * iv, v1.y * iv, v1.z * iv, v1.w * iv};                   \
        *(float4*)ap = w0;                                                          \
        *(float4*)(ap + 4) = w1;                                                    \
        union { ushort4 h[2]; uint4 q; } pk;                                        \
        pk.h[0] = (ushort4){f2bf(w0.x), f2bf(w0.y), f2bf(w0.z), f2bf(w0.w)};        \
        pk.h[1] = (ushort4){f2bf(w1.x), f2bf(w1.y), f2bf(w1.z), f2bf(w1.w)};        \
        *(uint4*)(sm + (buf)*8192 + tid * 16) = pk.q;                               \
    } while (0)

    PV_STAGE(0, 0);
    __syncthreads();
    for (int hp = 0; hp < 64; ++hp) {
        const int buf = hp & 1;
        if (hp < 63) PV_STAGE(buf ^ 1, hp + 1);
#pragma unroll
        for (int ks = 0; ks < 2; ++ks) {
            s16x8 af[2], bfr[4];
#pragma unroll
            for (int f = 0; f < 2; ++f) {
                int row = wr * 32 + f * 16 + (l & 15);
                int sl = (ks * 4 + (l >> 4)) ^ (row & 7);
                af[f] = *(const s16x8*)(sm + buf * 8192 + row * 128 + sl * 16);
            }
#pragma unroll
            for (int f = 0; f < 4; ++f) {
                int row = wc * 64 + f * 16 + (l & 15);
                int sl = (ks * 4 + (l >> 4)) ^ (row & 7);
                bfr[f] = *(const s16x8*)(sm + 16384 + buf * 32768 + row * 128 + sl * 16);
            }
#pragma unroll
            for (int i = 0; i < 2; ++i)
#pragma unroll
                for (int j = 0; j < 4; ++j)
                    acc[i][j] = __builtin_amdgcn_mfma_f32_16x16x32_bf16(af[i], bfr[j], acc[i][j], 0, 0, 0);
        }
        __syncthreads();
    }

#pragma unroll
    for (int i = 0; i < 2; ++i)
#pragma unroll
        for (int j = 0; j < 4; ++j)
#pragma unroll
            for (int r = 0; r < 4; ++r) {
                const int ii = ih * 64 + wr * 32 + i * 16 + (l >> 4) * 4 + r;
                const int dd = wc * 64 + j * 16 + (l & 15);
                Pb[((size_t)a * M + ii) * D + dd] = acc[i][j][r];
            }
}

// ---------------------------------------------------------------------------
// projo: out = (P0+P1) @ WoT^T + bo, fp32 out. B dbuf 2x4096 @16384.
// ---------------------------------------------------------------------------
__global__ __launch_bounds__(256) void projo_mfma(const float* __restrict__ P0,
                                                  const float* __restrict__ P1,
                                                  const unsigned short* __restrict__ WT,
                                                  const float* __restrict__ bias,
                                                  float* __restrict__ dst) {
    __shared__ __align__(16) char sm[24576];
    const int tid = threadIdx.x;
    const int w = tid >> 6, l = tid & 63;
    const int wi = w >> 1, wj = w & 1;
    const int m0 = blockIdx.y * 128;
    const int n0 = blockIdx.x * 64;

    const int s0 = tid, s1 = tid + 256;
    const int ar0 = s0 >> 2, ar1 = s1 >> 2;
    const int g0 = (((s0 & 3) ^ ((ar0 >> 1) & 3)) * 8);
    const int g1 = (((s1 & 3) ^ ((ar1 >> 1) & 3)) * 8);
    const int brw = tid >> 2;
    const int gb = (((tid & 3) ^ ((brw >> 1) & 3)) * 8);
    const size_t bsrc = (size_t)(n0 + brw) * D;
    const int slotp = (((l >> 4) ^ (((l & 15) >> 1) & 3)) << 4);

    f32x4 acc[4][2] = {};

#define PO_STAGE(buf, t)                                                        \
    do {                                                                        \
        int k0 = (t) * 32;                                                      \
        gld16(WT + bsrc + k0 + gb, sm + 16384 + (buf)*4096 + tid * 16);         \
        size_t f0 = (size_t)(m0 + ar0) * D + k0 + g0;                           \
        size_t f1 = (size_t)(m0 + ar1) * D + k0 + g1;                           \
        float4 a0 = *(const float4*)(P0 + f0), a1 = *(const float4*)(P0 + f0 + 4); \
        float4 b0 = *(const float4*)(P1 + f0), b1 = *(const float4*)(P1 + f0 + 4); \
        float4 c0 = *(const float4*)(P0 + f1), c1 = *(const float4*)(P0 + f1 + 4); \
        float4 d0 = *(const float4*)(P1 + f1), d1 = *(const float4*)(P1 + f1 + 4); \
        union { ushort4 h[2]; uint4 q; } pa, pb;                                \
        pa.h[0] = (ushort4){f2bf(a0.x + b0.x), f2bf(a0.y + b0.y), f2bf(a0.z + b0.z), f2bf(a0.w + b0.w)}; \
        pa.h[1] = (ushort4){f2bf(a1.x + b1.x), f2bf(a1.y + b1.y), f2bf(a1.z + b1.z), f2bf(a1.w + b1.w)}; \
        pb.h[0] = (ushort4){f2bf(c0.x + d0.x), f2bf(c0.y + d0.y), f2bf(c0.z + d0.z), f2bf(c0.w + d0.w)}; \
        pb.h[1] = (ushort4){f2bf(c1.x + d1.x), f2bf(c1.y + d1.y), f2bf(c1.z + d1.z), f2bf(c1.w + d1.w)}; \
        *(uint4*)(sm + (buf)*8192 + s0 * 16) = pa.q;                            \
        *(uint4*)(sm + (buf)*8192 + s1 * 16) = pb.q;                            \
    } while (0)

    PO_STAGE(0, 0);
    __syncthreads();
    for (int t = 0; t < 8; ++t) {
        const int buf = t & 1;
        if (t < 7) PO_STAGE(buf ^ 1, t + 1);
        s16x8 af[4], bfr[2];
#pragma unroll
        for (int f = 0; f < 4; ++f)
            af[f] = *(const s16x8*)(sm + buf * 8192 + (wi * 64 + f * 16 + (l & 15)) * 64 + slotp);
#pragma unroll
        for (int f = 0; f < 2; ++f)
            bfr[f] = *(const s16x8*)(sm + 16384 + buf * 4096 + (wj * 32 + f * 16 + (l & 15)) * 64 + slotp);
#pragma unroll
        for (int i = 0; i < 4; ++i)
#pragma unroll
            for (int j = 0; j < 2; ++j)
                acc[i][j] = __builtin_amdgcn_mfma_f32_16x16x32_bf16(af[i], bfr[j], acc[i][j], 0, 0, 0);
        __syncthreads();
    }

#pragma unroll
    for (int i = 0; i < 4; ++i)
#pragma unroll
        for (int j = 0; j < 2; ++j) {
            const int col = n0 + wj * 32 + j * 16 + (l & 15);
            const int row0 = m0 + wi * 64 + i * 16 + (l >> 4) * 4;
            const float bb = bias[col];
#pragma unroll
            for (int r = 0; r < 4; ++r)
                dst[(size_t)(row0 + r) * D + col] = acc[i][j][r] + bb;
        }
}

// ---------------------------------------------------------------------------
extern "C" void kernel_launch(void* const* d_in, const int* in_sizes, int n_in,
                              void* d_out, int out_size, void* d_ws, size_t ws_size,
                              hipStream_t stream) {
    const float* q    = (const float*)d_in[0];
    const float* k    = (const float*)d_in[1];
    const float* v    = (const float*)d_in[2];
    const float* mask = (const float*)d_in[3];
    const float* Wq   = (const float*)d_in[4];
    const float* bq   = (const float*)d_in[5];
    const float* Wk   = (const float*)d_in[6];
    const float* bk   = (const float*)d_in[7];
    const float* Wv   = (const float*)d_in[8];
    const float* bv   = (const float*)d_in[9];
    const float* Wo   = (const float*)d_in[10];
    const float* bo   = (const float*)d_in[11];

    float* out = (float*)d_out;                    // (G, M, D)
    float* att = out + (size_t)G * M * D;          // (G, G, M, M)

    char* ws = (char*)d_ws;
    unsigned short* qb  = (unsigned short*)(ws + 0);           // 64*129*256
    unsigned short* kb  = (unsigned short*)(ws + 4227072);
    unsigned short* vb  = (unsigned short*)(ws + 8454144);     // 64*128*256
    unsigned short* WqT = (unsigned short*)(ws + 12648448);
    unsigned short* WkT = (unsigned short*)(ws + 12648448 + 131072);
    unsigned short* WvT = (unsigned short*)(ws + 12648448 + 262144);
    unsigned short* WoT = (unsigned short*)(ws + 12648448 + 393216);
    unsigned short* Qbf = (unsigned short*)(ws + 13172736);
    unsigned short* Kbf = (unsigned short*)(ws + 17367040);
    unsigned short* Vt  = (unsigned short*)(ws + 21561344);
    float* P0      = (float*)(ws + 0);             // overlays qb+kb (dead after projections)
    float* P1      = (float*)(ws + 25755648);
    float* row_sum = (float*)(ws + 34144256);
    float* invb    = (float*)(ws + 34144768);

    dim3 blk(256);
    const int nq4 = (G * S * D) / 4;    // 132096 float4s
    const int nv4 = (G * M * D) / 4;
    cvt_kernel<<<(nq4 + 255) / 256, blk, 0, stream>>>(q, qb, nq4);
    cvt_kernel<<<(nq4 + 255) / 256, blk, 0, stream>>>(k, kb, nq4);
    cvt_kernel<<<(nv4 + 255) / 256, blk, 0, stream>>>(v, vb, nv4);
    wt_kernel<<<dim3(4, 4), blk, 0, stream>>>(Wq, WqT);
    wt_kernel<<<dim3(4, 4), blk, 0, stream>>>(Wk, WkT);
    wt_kernel<<<dim3(4, 4), blk, 0, stream>>>(Wv, WvT);
    wt_kernel<<<dim3(4, 4), blk, 0, stream>>>(Wo, WoT);

    hipMemsetAsync(row_sum, 0, 2 * G * sizeof(float), stream);

    dim3 gproj(D / 64, (G * M) / 128);             // (4, 64)
    proj_mfma<<<gproj, blk, 0, stream>>>(qb, WqT, bq, Qbf, S, 1, 0);
    proj_mfma<<<gproj, blk, 0, stream>>>(kb, WkT, bk, Kbf, S, 0, 0);
    proj_mfma<<<gproj, blk, 0, stream>>>(vb, WvT, bv, Vt, M, 0, 1);

    scores_mfma<<<dim3(G * G), blk, 0, stream>>>(Qbf, Kbf, mask, att, row_sum);

    inv_kernel<<<1, 128, 0, stream>>>(row_sum, invb);

    pv2<<<dim3(2, 2, G), dim3(512), 0, stream>>>(att, Vt, invb, P0, P1);

    projo_mfma<<<gproj, blk, 0, stream>>>(P0, P1, WoT, bo, out);
}